// Round 1
// baseline (169.204 us; speedup 1.0000x reference)
//
#include <hip/hip_runtime.h>

// pyramid_roi_align (Mask R-CNN), MI355X.
// R4: replace divergent float2 gathers (TA-bound, ~64cy/wave-load -> 98k cy/CU
// = the measured 41us) with coalesced float4 LDS staging. Per box, each channel
// needs only 14 rows x <=32-col window (FPN routes boxes to ~14x14 px). Stage
// 8 channels/group into LDS with dwordx4 loads (8 lanes/row, coalesced), then
// bilinear taps from LDS. Wide-aspect boxes (window > 32 cols, ~10%) take a
// block-uniform fallback identical to the proven R3 gather path.

#define POOL 7
#define NCH  256
#define ELEMS_PER_BOX (NCH * POOL * POOL)    // 12544
#define HALF_ELEMS (ELEMS_PER_BOX / 2)       // 6272
#define CG 8                                 // channels per staging group
#define NGROUPS 16                           // 128 channels per block / CG
#define ROWS 14                              // 2 rows (y0,y1) per py
#define SA 32                                // staged window width (floats)
#define SROW 36                              // padded row stride (144B, 16B-aligned)
#define GROUP_OUT (CG * 49)                  // 392 outputs per group

typedef float f2 __attribute__((ext_vector_type(2)));
typedef float f4 __attribute__((ext_vector_type(4)));

__global__ __launch_bounds__(256, 8) void roi_align_kernel(
    const float* __restrict__ boxes,
    const float* __restrict__ p2, const float* __restrict__ p3,
    const float* __restrict__ p4, const float* __restrict__ p5,
    float* __restrict__ out, int N)
{
    const int bid  = blockIdx.x;
    const int n    = bid >> 1;      // box
    const int half = bid & 1;       // channel half: [0,128) or [128,256)

    __shared__ float s_stage[CG * ROWS * SROW];   // 16128 B
    __shared__ float s_a[49], s_b[49], s_w0[49], s_w1[49];
    __shared__ int   s_dx[49];                    // xb - xb0a (float index in window)
    __shared__ int   s_off0[49], s_off1[49];      // fallback gather offsets
    __shared__ int   s_rowoff[ROWS];              // y*W for the 14 rows
    __shared__ int   s_HW, s_xb0a, s_sa4, s_fast;
    __shared__ const float* s_fmap;

    const int tid = threadIdx.x;

    if (tid < 49) {
        const float by1 = boxes[4 * n + 0];
        const float bx1 = boxes[4 * n + 1];
        const float by2 = boxes[4 * n + 2];
        const float bx2 = boxes[4 * n + 3];
        const float h = by2 - by1;
        const float w = bx2 - bx1;
        float rl = 4.0f + log2f(sqrtf(h * w) / 0.21875f);
        int level = (int)rintf(rl);            // round-half-even = jnp.round
        level = min(5, max(2, level));
        const int H = 256 >> (level - 2);
        const int W = H;
        const int py = tid / 7;
        const int px = tid - 7 * py;

        // y interp
        const float ty = (float)py / 6.0f;
        const float ys = (by1 + ty * (by2 - by1)) * (float)(H - 1);
        const float yf = floorf(ys);
        const float ly = ys - yf;
        int y0 = (int)yf; y0 = min(H - 1, max(0, y0));
        const int y1 = min(H - 1, y0 + 1);
        const float vy = (ys >= 0.0f && ys <= (float)(H - 1)) ? 1.0f : 0.0f;

        // x interp
        const float tx = (float)px / 6.0f;
        const float xs = (bx1 + tx * (bx2 - bx1)) * (float)(W - 1);
        const float xf = floorf(xs);
        const float lx = xs - xf;
        int x0 = (int)xf; x0 = min(W - 1, max(0, x0));
        const float vx = (xs >= 0.0f && xs <= (float)(W - 1)) ? 1.0f : 0.0f;
        const int xb = min(x0, W - 2);         // float2 base column
        const bool edge = (x0 != xb);
        const float a = edge ? 0.0f : vx * (1.0f - lx);
        const float b = edge ? vx : vx * lx;

        // column window: recompute endpoints with the SAME expressions (tx=0,1)
        // so every thread derives identical xb0a/sa4/fast without extra barriers.
        const float xsA = (bx1 + 0.0f * (bx2 - bx1)) * (float)(W - 1);
        int xA = (int)floorf(xsA); xA = min(W - 1, max(0, xA));
        const int xbA = min(xA, W - 2);
        const float xsB = (bx1 + 1.0f * (bx2 - bx1)) * (float)(W - 1);
        int xB = (int)floorf(xsB); xB = min(W - 1, max(0, xB));
        const int xbB = min(xB, W - 2);
        const int xb0a = min(xbA & ~3, W - SA);   // 16B-aligned, window fits plane
        const int need = xbB + 2 - xb0a;          // cols needed from xb0a

        s_off0[tid] = y0 * W + xb;
        s_off1[tid] = y1 * W + xb;
        s_a[tid] = a;
        s_b[tid] = b;
        s_w0[tid] = vy * (1.0f - ly);
        s_w1[tid] = vy * ly;
        s_dx[tid] = xb - xb0a;
        if (px == 0) {
            s_rowoff[2 * py]     = y0 * W;
            s_rowoff[2 * py + 1] = y1 * W;
        }
        if (tid == 0) {
            s_HW = H * W;
            s_fmap = (level == 2) ? p2 : (level == 3) ? p3 : (level == 4) ? p4 : p5;
            s_xb0a = xb0a;
            s_sa4  = (need + 3) >> 2;             // float4s per row, 1..8
            s_fast = (need <= SA) ? 1 : 0;
        }
    }
    __syncthreads();

    const int HW = s_HW;
    const float* __restrict__ fbase = s_fmap + (size_t)(half * 128) * HW;
    float* __restrict__ op = out + (size_t)n * ELEMS_PER_BOX + half * HALF_ELEMS;

    // two output slots per thread per group (392 = 256 + 136)
    const int c1  = tid / 49,  p1  = tid - 49 * c1;
    const int o2  = 256 + tid;
    const int c2  = o2 / 49,   p2i = o2 - 49 * c2;
    const bool act2 = (tid < GROUP_OUT - 256);

    const float a1 = s_a[p1],  b1 = s_b[p1],  w01 = s_w0[p1],  w11 = s_w1[p1];
    const float a2 = s_a[p2i], b2 = s_b[p2i], w02 = s_w0[p2i], w12 = s_w1[p2i];

    if (s_fast) {
        const int sa4  = s_sa4;
        const int xb0a = s_xb0a;

        // staging slots: flat idx -> (rid = row slot 0..111, q = float4 col 0..7)
        int goff[4], lw[4];
        bool gact[4];
#pragma unroll
        for (int pp = 0; pp < 4; ++pp) {
            const int idx = pp * 256 + tid;
            const int rid = idx >> 3;
            const int q   = idx & 7;
            gact[pp] = (rid < CG * ROWS) && (q < sa4);
            const int cl = rid / 14;
            const int r  = rid - 14 * cl;
            lw[pp]   = rid * SROW + q * 4;                      // float index in LDS
            goff[pp] = cl * HW + s_rowoff[r] + xb0a + q * 4;    // float index in plane
        }

        // per-thread tap bases (constant across groups)
        const int t1 = (c1 * ROWS + 2 * (p1 / 7)) * SROW + s_dx[p1];
        const int t2 = (c2 * ROWS + 2 * (p2i / 7)) * SROW + s_dx[p2i];

        for (int g = 0; g < NGROUPS; ++g) {
            const float* fg = fbase + (size_t)(g * CG) * HW;
            f4 v[4];
#pragma unroll
            for (int pp = 0; pp < 4; ++pp)
                if (gact[pp]) v[pp] = *(const f4*)(fg + goff[pp]);
#pragma unroll
            for (int pp = 0; pp < 4; ++pp)
                if (gact[pp]) *(f4*)(&s_stage[lw[pp]]) = v[pp];
            __syncthreads();

            {
                const float t00 = s_stage[t1],        t01 = s_stage[t1 + 1];
                const float t10 = s_stage[t1 + SROW], t11 = s_stage[t1 + SROW + 1];
                const float r0 = t00 * a1 + t01 * b1;
                const float r1 = t10 * a1 + t11 * b1;
                op[g * GROUP_OUT + tid] = r0 * w01 + r1 * w11;
            }
            if (act2) {
                const float u00 = s_stage[t2],        u01 = s_stage[t2 + 1];
                const float u10 = s_stage[t2 + SROW], u11 = s_stage[t2 + SROW + 1];
                const float s0 = u00 * a2 + u01 * b2;
                const float s1 = u10 * a2 + u11 * b2;
                op[g * GROUP_OUT + 256 + tid] = s0 * w02 + s1 * w12;
            }
            __syncthreads();   // before next group's staging overwrites
        }
    } else {
        // wide-window fallback: proven R3-style float2 gathers, same output map
        const int off01 = s_off0[p1],  off11 = s_off1[p1];
        const int off02 = s_off0[p2i], off12 = s_off1[p2i];
        for (int g = 0; g < NGROUPS; ++g) {
            const float* pl1 = fbase + (size_t)(g * CG + c1) * HW;
            const f2 q0 = *(const f2*)(pl1 + off01);
            const f2 q1 = *(const f2*)(pl1 + off11);
            const float r0 = q0.x * a1 + q0.y * b1;
            const float r1 = q1.x * a1 + q1.y * b1;
            op[g * GROUP_OUT + tid] = r0 * w01 + r1 * w11;
            if (act2) {
                const float* pl2 = fbase + (size_t)(g * CG + c2) * HW;
                const f2 u0 = *(const f2*)(pl2 + off02);
                const f2 u1 = *(const f2*)(pl2 + off12);
                const float s0 = u0.x * a2 + u0.y * b2;
                const float s1 = u1.x * a2 + u1.y * b2;
                op[g * GROUP_OUT + 256 + tid] = s0 * w02 + s1 * w12;
            }
        }
    }
}

extern "C" void kernel_launch(void* const* d_in, const int* in_sizes, int n_in,
                              void* d_out, int out_size, void* d_ws, size_t ws_size,
                              hipStream_t stream) {
    const float* boxes = (const float*)d_in[0];
    const float* p2    = (const float*)d_in[1];
    const float* p3    = (const float*)d_in[2];
    const float* p4    = (const float*)d_in[3];
    const float* p5    = (const float*)d_in[4];
    float* out = (float*)d_out;
    const int N = in_sizes[0] / 4;

    roi_align_kernel<<<N * 2, 256, 0, stream>>>(boxes, p2, p3, p4, p5, out, N);
}